// Round 1
// baseline (31.629 us; speedup 1.0000x reference)
//
#include <hip/hip_runtime.h>
#include <hip/hip_bf16.h>

// Problem: out[b,h,i,j] = mask[b,h,i,j] - bias[h,i,j]
// where bias[h,i,j] = MLP(i - j) -- depends only on d = i - j + (L-1).
// So: (1) build 2047x8 table, (2) stream mask - table.

#define L_SEQ 1024
#define NDIAG (2 * L_SEQ - 1)   // 2047
#define NH 8
#define DIM 64

__device__ __forceinline__ float silu_f(float x) {
    return x / (1.0f + __expf(-x));
}

// One block per diagonal value d in [0, 2047); 64 threads (= DIM) per block.
__global__ __launch_bounds__(DIM) void build_bias_table(
    const float* __restrict__ W0, const float* __restrict__ b0,
    const float* __restrict__ W1, const float* __restrict__ b1,
    const float* __restrict__ W2, const float* __restrict__ b2,
    const float* __restrict__ Wf, const float* __restrict__ bf,
    float* __restrict__ tab /* [NH][NDIAG] */) {
    const int d = blockIdx.x;        // 0..2046
    const int t = threadIdx.x;       // 0..63
    const float rel = (float)(d - (L_SEQ - 1));   // i - j

    __shared__ float sh[DIM];

    // layer 0: (1 -> 64)
    float h = silu_f(rel * W0[t] + b0[t]);
    sh[t] = h;
    __syncthreads();

    // layer 1: (64 -> 64)
    float acc = b1[t];
    #pragma unroll
    for (int k = 0; k < DIM; ++k) acc += sh[k] * W1[k * DIM + t];
    float h1 = silu_f(acc);
    __syncthreads();
    sh[t] = h1;
    __syncthreads();

    // layer 2: (64 -> 64)
    acc = b2[t];
    #pragma unroll
    for (int k = 0; k < DIM; ++k) acc += sh[k] * W2[k * DIM + t];
    float h2 = silu_f(acc);
    __syncthreads();
    sh[t] = h2;
    __syncthreads();

    // final: (64 -> 8)
    if (t < NH) {
        float a = bf[t];
        #pragma unroll
        for (int k = 0; k < DIM; ++k) a += sh[k] * Wf[k * NH + t];
        tab[t * NDIAG + d] = a;
    }
}

// out = mask - tab[h][i - j + 1023], vectorized float4 (L % 4 == 0).
__global__ __launch_bounds__(256) void apply_bias(
    const float4* __restrict__ mask, const float* __restrict__ tab,
    float4* __restrict__ out, int n4) {
    int idx = blockIdx.x * blockDim.x + threadIdx.x;
    const int stride = gridDim.x * blockDim.x;
    for (; idx < n4; idx += stride) {
        const int n = idx << 2;                 // flat element index
        const int j = n & (L_SEQ - 1);
        const int i = (n >> 10) & (L_SEQ - 1);
        const int h = (n >> 20) & (NH - 1);
        const float* tb = tab + h * NDIAG + (i - j + (L_SEQ - 1));
        const float4 m = mask[idx];
        float4 o;
        o.x = m.x - tb[0];
        o.y = m.y - tb[-1];
        o.z = m.z - tb[-2];
        o.w = m.w - tb[-3];
        out[idx] = o;
    }
}

extern "C" void kernel_launch(void* const* d_in, const int* in_sizes, int n_in,
                              void* d_out, int out_size, void* d_ws, size_t ws_size,
                              hipStream_t stream) {
    // setup_inputs order:
    // 0: mask (B,NH,L,L) f32
    // 1: q, 2: k, 3: v            (unused -- reference only uses shapes)
    // 4: W0 (1,64)  5: b0 (64)
    // 6: W1 (64,64) 7: b1 (64)
    // 8: W2 (64,64) 9: b2 (64)
    // 10: Wf (64,8) 11: bf (8)
    const float* mask = (const float*)d_in[0];
    const float* W0 = (const float*)d_in[4];
    const float* b0 = (const float*)d_in[5];
    const float* W1 = (const float*)d_in[6];
    const float* b1 = (const float*)d_in[7];
    const float* W2 = (const float*)d_in[8];
    const float* b2 = (const float*)d_in[9];
    const float* Wf = (const float*)d_in[10];
    const float* bf = (const float*)d_in[11];
    float* out = (float*)d_out;

    float* tab = (float*)d_ws;   // NH * NDIAG floats = 64 KiB

    build_bias_table<<<NDIAG, DIM, 0, stream>>>(W0, b0, W1, b1, W2, b2, Wf, bf, tab);

    const int n4 = out_size / 4;             // 4,194,304
    const int block = 256;
    const int grid = 2048;                    // grid-stride, ~8 iters/thread
    apply_bias<<<grid, block, 0, stream>>>(
        (const float4*)mask, tab, (float4*)out, n4);
}